// Round 1
// baseline (213.181 us; speedup 1.0000x reference)
//
#include <hip/hip_runtime.h>
#include <stdint.h>

typedef __attribute__((ext_vector_type(2))) float  f32x2;
typedef __attribute__((ext_vector_type(4))) float  f32x4;
typedef __attribute__((ext_vector_type(2))) __bf16 bf16x2;
typedef __attribute__((ext_vector_type(8))) __bf16 bf16x8;

#define N_B    4096
#define N_K    8192
#define DDIM   512
#define VD     512
#define SPLITK 4

#define GLL(g, l) __builtin_amdgcn_global_load_lds(                      \
    (const __attribute__((address_space(1))) void*)(g),                  \
    (__attribute__((address_space(3))) void*)(l), 16, 0, 0)

// ---------------- prep: f32 -> bf16 rows + row sum of squares ----------------
__global__ void prep_rows(const float* __restrict__ src, __bf16* __restrict__ dst,
                          float* __restrict__ sq)
{
  const int row = blockIdx.x;
  const int tid = threadIdx.x;                       // 256 threads, 512 cols
  f32x2 v = ((const f32x2*)(src + (size_t)row * DDIM))[tid];
  float ss = v[0] * v[0] + v[1] * v[1];
  bf16x2 o; o[0] = (__bf16)v[0]; o[1] = (__bf16)v[1];
  ((bf16x2*)(dst + (size_t)row * DDIM))[tid] = o;
  #pragma unroll
  for (int m = 1; m < 64; m <<= 1) ss += __shfl_xor(ss, m);
  __shared__ float red[4];
  if ((tid & 63) == 0) red[tid >> 6] = ss;
  __syncthreads();
  if (tid == 0) sq[row] = red[0] + red[1] + red[2] + red[3];
}

// ---------------- prep: V [N_K][VD] f32 -> VT [VD][N_K] bf16 ----------------
__global__ void prep_vT(const float* __restrict__ V, __bf16* __restrict__ VT)
{
  __shared__ __bf16 t[64][72];                       // +8 pad
  const int n0 = blockIdx.x * 64;
  const int d0 = blockIdx.y * 64;
  const int tid = threadIdx.x;                       // 256
  const int lr = tid >> 4, lc = tid & 15;
  #pragma unroll
  for (int p = 0; p < 4; p++) {
    const int r = p * 16 + lr;
    f32x4 v = *(const f32x4*)(V + (size_t)(n0 + r) * VD + d0 + lc * 4);
    t[r][lc * 4 + 0] = (__bf16)v[0];
    t[r][lc * 4 + 1] = (__bf16)v[1];
    t[r][lc * 4 + 2] = (__bf16)v[2];
    t[r][lc * 4 + 3] = (__bf16)v[3];
  }
  __syncthreads();
  const int od = tid >> 6, oc = tid & 63;
  #pragma unroll
  for (int p = 0; p < 16; p++) {
    const int d = p * 4 + od;
    VT[(size_t)(d0 + d) * N_K + n0 + oc] = t[oc][d];
  }
}

// ---------------- main GEMM (both inputs row-major [rows][K], i.e. B^T form) -
// MODE 0: S = b @ K^T -> w = 1/max(bsq+ksq-2S, 1e-6); store w bf16; atomic row sums
// MODE 1: P = w @ V  (via VT) -> fp32 partial per split-K slice
template<int MODE>
__global__ void __launch_bounds__(256, 2)
gemm_bt(const __bf16* __restrict__ Amat, const __bf16* __restrict__ Bmat,
        const int ldaE, const int ldbE, const int kPerSplit,
        const float* __restrict__ bsq, const float* __restrict__ ksq,
        __bf16* __restrict__ Wout, float* __restrict__ sumw,
        float* __restrict__ Pout)
{
  __shared__ __bf16 Asm[128 * 64];                   // 16 KB, rows of 128 B
  __shared__ __bf16 Bsm[128 * 64];

  const int tid  = threadIdx.x;
  const int wid  = tid >> 6;
  const int lane = tid & 63;
  const int wm = wid >> 1, wn = wid & 1;             // 2x2 waves, 64x64 each
  const int r15 = lane & 15, hi = lane >> 4;

  const int m0 = blockIdx.y * 128;
  const int n0 = blockIdx.x * 128;
  const long kBegin = (long)blockIdx.z * kPerSplit;

  // staging geometry: one global_load_lds covers 8 rows (8 lanes/row of 16B).
  // XOR swizzle (chunk ^= row&7) applied on the GLOBAL source; LDS dest linear.
  const int srow   = lane >> 3;                      // 0..7
  const int schunk = (lane & 7) ^ srow;              // swizzled 16B chunk

  const __bf16* aSrc = Amat + (size_t)(m0 + wid * 32 + srow) * ldaE + kBegin + schunk * 8;
  const __bf16* bSrc = Bmat + (size_t)(n0 + wid * 32 + srow) * ldbE + kBegin + schunk * 8;
  __bf16* aDst = &Asm[wid * 32 * 64];
  __bf16* bDst = &Bsm[wid * 32 * 64];

  const f32x4 fzero = {0.f, 0.f, 0.f, 0.f};
  f32x4 acc[4][4];
  #pragma unroll
  for (int i = 0; i < 4; i++)
    #pragma unroll
    for (int j = 0; j < 4; j++) acc[i][j] = fzero;

  for (int k0 = 0; k0 < kPerSplit; k0 += 64) {
    __syncthreads();                                 // prev compute done
    #pragma unroll
    for (int i = 0; i < 4; i++) {
      GLL(aSrc + (size_t)i * 8 * ldaE + k0, aDst + i * 8 * 64);
      GLL(bSrc + (size_t)i * 8 * ldbE + k0, bDst + i * 8 * 64);
    }
    __syncthreads();                                 // drains vmcnt(0)
    #pragma unroll
    for (int kk = 0; kk < 2; kk++) {                 // two k=32 MFMA steps
      bf16x8 af[4], bfr[4];
      #pragma unroll
      for (int mf = 0; mf < 4; mf++) {
        const int cs = ((kk << 2) + hi) ^ (r15 & 7); // swizzled read chunk
        af[mf] = *(const bf16x8*)((const char*)Asm +
                   (wm * 64 + mf * 16 + r15) * 128 + cs * 16);
      }
      #pragma unroll
      for (int nf = 0; nf < 4; nf++) {
        const int cs = ((kk << 2) + hi) ^ (r15 & 7);
        bfr[nf] = *(const bf16x8*)((const char*)Bsm +
                    (wn * 64 + nf * 16 + r15) * 128 + cs * 16);
      }
      #pragma unroll
      for (int mf = 0; mf < 4; mf++)
        #pragma unroll
        for (int nf = 0; nf < 4; nf++)
          acc[mf][nf] = __builtin_amdgcn_mfma_f32_16x16x32_bf16(
              af[mf], bfr[nf], acc[mf][nf], 0, 0, 0);
    }
  }

  if constexpr (MODE == 0) {
    float kq[4];
    #pragma unroll
    for (int nf = 0; nf < 4; nf++) kq[nf] = ksq[n0 + wn * 64 + nf * 16 + r15];
    #pragma unroll
    for (int mf = 0; mf < 4; mf++) {
      const int rowb = m0 + wm * 64 + mf * 16 + hi * 4;   // +r for C row
      const f32x4 bq = *(const f32x4*)(bsq + rowb);
      float rsum[4] = {0.f, 0.f, 0.f, 0.f};
      #pragma unroll
      for (int nf = 0; nf < 4; nf++) {
        const int col = n0 + wn * 64 + nf * 16 + r15;
        #pragma unroll
        for (int r = 0; r < 4; r++) {
          const float d2 = bq[r] + kq[nf] - 2.0f * acc[mf][nf][r];
          const float w  = 1.0f / fmaxf(d2, 1e-6f);
          rsum[r] += w;
          Wout[(size_t)(rowb + r) * N_K + col] = (__bf16)w;
        }
      }
      #pragma unroll
      for (int r = 0; r < 4; r++) {
        float tsum = rsum[r];
        tsum += __shfl_xor(tsum, 1);
        tsum += __shfl_xor(tsum, 2);
        tsum += __shfl_xor(tsum, 4);
        tsum += __shfl_xor(tsum, 8);
        if (r15 == 0) atomicAdd(&sumw[rowb + r], tsum);
      }
    }
  } else {
    float* op = Pout + (size_t)blockIdx.z * N_B * VD;
    #pragma unroll
    for (int mf = 0; mf < 4; mf++) {
      const int rowb = m0 + wm * 64 + mf * 16 + hi * 4;
      #pragma unroll
      for (int nf = 0; nf < 4; nf++) {
        const int col = n0 + wn * 64 + nf * 16 + r15;
        #pragma unroll
        for (int r = 0; r < 4; r++)
          op[(size_t)(rowb + r) * VD + col] = acc[mf][nf][r];
      }
    }
  }
}

// ---------------- reduce split-K partials + normalize by sum_w ----------------
__global__ void reduce_norm(const float* __restrict__ part, const float* __restrict__ sumw,
                            float* __restrict__ out)
{
  const int idx = blockIdx.x * 256 + threadIdx.x;    // f32x4 index
  const size_t stride = (size_t)N_B * VD / 4;
  const f32x4* p = (const f32x4*)part;
  f32x4 s = p[idx] + p[idx + stride] + p[idx + 2 * stride] + p[idx + 3 * stride];
  const float inv = 1.0f / sumw[idx >> 7];           // 128 f32x4 per row
  ((f32x4*)out)[idx] = s * inv;
}

extern "C" void kernel_launch(void* const* d_in, const int* in_sizes, int n_in,
                              void* d_out, int out_size, void* d_ws, size_t ws_size,
                              hipStream_t stream)
{
  const float* b = (const float*)d_in[0];
  const float* K = (const float*)d_in[1];
  const float* V = (const float*)d_in[2];
  float* out = (float*)d_out;
  (void)in_sizes; (void)n_in; (void)out_size; (void)ws_size;

  char* ws = (char*)d_ws;
  size_t off = 0;
  auto alloc = [&](size_t bytes) -> void* {
    void* p = ws + off;
    off += (bytes + 255) & ~(size_t)255;
    return p;
  };
  __bf16* b_bf  = (__bf16*)alloc((size_t)N_B * DDIM * 2);      //   4 MB
  __bf16* K_bf  = (__bf16*)alloc((size_t)N_K * DDIM * 2);      //   8 MB
  __bf16* V_T   = (__bf16*)alloc((size_t)VD * N_K * 2);        //   8 MB
  float*  b_sq  = (float*)alloc((size_t)N_B * 4);
  float*  k_sq  = (float*)alloc((size_t)N_K * 4);
  float*  sum_w = (float*)alloc((size_t)N_B * 4);
  __bf16* w_bf  = (__bf16*)alloc((size_t)N_B * N_K * 2);       //  64 MB
  float*  part  = (float*)alloc((size_t)SPLITK * N_B * VD * 4);//  32 MB

  hipMemsetAsync(sum_w, 0, N_B * 4, stream);
  prep_rows<<<N_B, 256, 0, stream>>>(b, b_bf, b_sq);
  prep_rows<<<N_K, 256, 0, stream>>>(K, K_bf, k_sq);
  prep_vT<<<dim3(N_K / 64, VD / 64), 256, 0, stream>>>(V, V_T);
  gemm_bt<0><<<dim3(N_K / 128, N_B / 128, 1), 256, 0, stream>>>(
      b_bf, K_bf, DDIM, DDIM, DDIM, b_sq, k_sq, w_bf, sum_w, nullptr);
  gemm_bt<1><<<dim3(VD / 128, N_B / 128, SPLITK), 256, 0, stream>>>(
      w_bf, V_T, N_K, N_K, N_K / SPLITK, nullptr, nullptr, nullptr, nullptr, part);
  reduce_norm<<<(N_B * VD / 4) / 256, 256, 0, stream>>>(part, sum_w, out);
}